// Round 20
// baseline (207.771 us; speedup 1.0000x reference)
//
#include <hip/hip_runtime.h>

#define NODE_DIM 32
#define EDGE_DIM 16
#define DD 48          // NODE_DIM + EDGE_DIM
#define OUT_DIM 32
#define MAXDEG 64      // bucket capacity (Poisson(16): max deg ~44)
#define NXCD 8
#define NPW 16         // nodes per wave (one MFMA M-tile for the node MLP)

typedef _Float16 f16x8 __attribute__((ext_vector_type(8)));
typedef float f32x4 __attribute__((ext_vector_type(4)));

// ---------------------------------------------------------------------------
// 1) prep (pure streaming, own kernel — r18 proved merging with the atomic
//    scatter serializes + interferes): y -> fp16; ex -> fp16
// ---------------------------------------------------------------------------
__global__ __launch_bounds__(256)
void prep_kernel(const float* __restrict__ y, _Float16* __restrict__ yh, int CBy,
                 const float* __restrict__ ex, _Float16* __restrict__ exh,
                 int N, int E) {
    int b = blockIdx.x;
    if (b < CBy) {   // y -> fp16, 8 floats/thread
        size_t i = ((size_t)b * 256 + threadIdx.x) * 8;
        if (i < (size_t)N * NODE_DIM) {
            const float4* s0 = reinterpret_cast<const float4*>(y + i);
            const float4 a = s0[0], c = s0[1];
            f16x8 h = {(_Float16)a.x, (_Float16)a.y, (_Float16)a.z, (_Float16)a.w,
                       (_Float16)c.x, (_Float16)c.y, (_Float16)c.z, (_Float16)c.w};
            *reinterpret_cast<f16x8*>(yh + i) = h;
        }
        return;
    }
    b -= CBy;        // ex -> fp16, 8 floats/thread
    size_t i = ((size_t)b * 256 + threadIdx.x) * 8;
    if (i < (size_t)E * EDGE_DIM) {
        const float4* s0 = reinterpret_cast<const float4*>(ex + i);
        const float4 a = s0[0], c = s0[1];
        f16x8 h = {(_Float16)a.x, (_Float16)a.y, (_Float16)a.z, (_Float16)a.w,
                   (_Float16)c.x, (_Float16)c.y, (_Float16)c.z, (_Float16)c.w};
        *reinterpret_cast<f16x8*>(exh + i) = h;
    }
}

// ---------------------------------------------------------------------------
// 2) scatter, XCD-partitioned (own kernel, proven ~45us)
// ---------------------------------------------------------------------------
__global__ __launch_bounds__(256)
void scatter_kernel(const int* __restrict__ dst, const int* __restrict__ src,
                    int* __restrict__ cursor, int2* __restrict__ meta,
                    int E, int NP) {
    const int xcd = blockIdx.x & (NXCD - 1);
    const int c   = blockIdx.x >> 3;
    const int base = c * 2048 + threadIdx.x * 8;
    if (base >= E) return;

    int dv[8], sv[8];
    if (base + 8 <= E) {
        *reinterpret_cast<int4*>(dv)     = *reinterpret_cast<const int4*>(dst + base);
        *reinterpret_cast<int4*>(dv + 4) = *reinterpret_cast<const int4*>(dst + base + 4);
        *reinterpret_cast<int4*>(sv)     = *reinterpret_cast<const int4*>(src + base);
        *reinterpret_cast<int4*>(sv + 4) = *reinterpret_cast<const int4*>(src + base + 4);
    } else {
#pragma unroll
        for (int i = 0; i < 8; ++i) {
            dv[i] = (base + i < E) ? dst[base + i] : -1;
            sv[i] = (base + i < E) ? src[base + i] : 0;
        }
    }
#pragma unroll
    for (int i = 0; i < 8; ++i) {
        const int d = dv[i];
        if (d >= 0 && (d & (NXCD - 1)) == xcd && base + i < E) {
            int pos = atomicAdd(&cursor[xcd * NP + (d >> 3)], 1);
            if (pos < MAXDEG)
                meta[(size_t)d * MAXDEG + pos] = make_int2(base + i, sv[i]);
        }
    }
}

// ---------------------------------------------------------------------------
// 3) fused (r18 version — half-batch meta staging, 24 KB LDS, 6 blocks/CU):
//    each wave owns 16 nodes; MFMA edge-MLP -> shfl reduce -> fp16 z-row
//    (k48=1 activates b2); epilogue node MLP = 4 MFMAs, coalesced stores.
// ---------------------------------------------------------------------------
__global__ __launch_bounds__(256)
void fused_kernel(const _Float16* __restrict__ yh, const _Float16* __restrict__ exh,
                  const float* __restrict__ W1, const float* __restrict__ b1,
                  const float* __restrict__ W2, const float* __restrict__ b2,
                  const int* __restrict__ cursor, const int2* __restrict__ meta,
                  float* __restrict__ out, int N, int NP) {
    __shared__ int2 mlds[4][8][MAXDEG];    // 16 KB: 8-node half-batch
    __shared__ _Float16 zl[4][NPW][64];    // 8 KB: z rows (48 z | 1.0 | 0s)

    const int wave = threadIdx.x >> 6;
    const int lane = threadIdx.x & 63;
    const int col = lane & 15;            // MFMA col / A-row index
    const int kg  = lane >> 4;            // k-group 0..3

    // --- edge-MLP B fragments (W1; b1 folded at kg==3, j==7 of Bhi) ---
    f16x8 Blo[3], Bhi[3];
#pragma unroll
    for (int t = 0; t < 3; ++t) {
        const float* wr = W1 + (size_t)(t * 16 + col) * DD;
#pragma unroll
        for (int j = 0; j < 8; ++j) {
            Blo[t][j] = (_Float16)wr[kg * 8 + j];
            Bhi[t][j] = (_Float16)0.f;
        }
        if (kg < 2) {
#pragma unroll
            for (int j = 0; j < 8; ++j)
                Bhi[t][j] = (_Float16)wr[NODE_DIM + kg * 8 + j];
        }
        if (kg == 3) Bhi[t][7] = (_Float16)b1[t * 16 + col];
    }

    // --- node-MLP B fragments: B[k][col] = W2[t*16+col][k]; b2 at k==48 ---
    f16x8 Wf[2][2];
#pragma unroll
    for (int t = 0; t < 2; ++t) {
#pragma unroll
        for (int c = 0; c < 2; ++c) {
            f16x8 v;
#pragma unroll
            for (int j = 0; j < 8; ++j) {
                const int k = c * 32 + kg * 8 + j;
                float w = 0.f;
                if (k < DD)       w = W2[(size_t)(t * 16 + col) * DD + k];
                else if (k == DD) w = b2[t * 16 + col];
                v[j] = (_Float16)w;
            }
            Wf[t][c] = v;
        }
    }

    const int nb0 = (blockIdx.x * 4 + wave) * NPW;

    // --- one lane-parallel cursor load for all 16 nodes ---
    int dgv = 0;
    if (lane < NPW) {
        const int n = nb0 + lane;
        if (n < N) dgv = cursor[(n & (NXCD - 1)) * NP + (n >> 3)];
    }

    // --- stage an 8-node half-batch of buckets into LDS ---
    auto stage8 = [&](int b0) {
#pragma unroll
        for (int k = 0; k < 8; ++k) {
            const int ni = b0 + k;
            const int cnt_i = min(__shfl(dgv, ni), MAXDEG);
            const int n = nb0 + ni;
            mlds[wave][k][lane] = (lane < cnt_i && n < N)
                                      ? meta[(size_t)n * MAXDEG + lane]
                                      : make_int2(0, 0);
        }
    };
    stage8(0);
    __builtin_amdgcn_wave_barrier();

    for (int ni = 0; ni < NPW; ++ni) {
        if (ni == 8) {                    // restage: nodes 0..7 already done
            __builtin_amdgcn_wave_barrier();
            stage8(8);
            __builtin_amdgcn_wave_barrier();
        }
        const int slot = ni & 7;
        const int n = nb0 + ni;
        const int dg = __shfl(dgv, ni);
        const int cnt = min(dg, MAXDEG);

        float pacc0 = 0.f, pacc1 = 0.f, pacc2 = 0.f;
        const int ngroups = (cnt + 15) >> 4;

        for (int g = 0; g < ngroups; ++g) {
            const bool valid = (g * 16 + col) < cnt;
            const int2 md = mlds[wave][slot][g * 16 + col];
            const int eid = md.x, sv = md.y;

            f16x8 alo = *reinterpret_cast<const f16x8*>(
                yh + (size_t)sv * NODE_DIM + kg * 8);

            f16x8 ahi;
            if (kg < 2) {
                ahi = *reinterpret_cast<const f16x8*>(
                    exh + (size_t)eid * EDGE_DIM + kg * 8);
            } else {
#pragma unroll
                for (int j = 0; j < 8; ++j) ahi[j] = (_Float16)0.f;
                if (kg == 3) ahi[7] = (_Float16)1.f;   // activates b1
            }

            if (!valid) {   // pads contribute exactly 0
#pragma unroll
                for (int j = 0; j < 8; ++j) { alo[j] = (_Float16)0.f; ahi[j] = (_Float16)0.f; }
            }

#pragma unroll
            for (int t = 0; t < 3; ++t) {
                f32x4 c = {0.f, 0.f, 0.f, 0.f};
                c = __builtin_amdgcn_mfma_f32_16x16x32_f16(alo, Blo[t], c, 0, 0, 0);
                c = __builtin_amdgcn_mfma_f32_16x16x32_f16(ahi, Bhi[t], c, 0, 0, 0);
#pragma unroll
                for (int r = 0; r < 4; ++r) {
                    const float v = fmaxf(c[r], 0.f);  // b1 already inside
                    if (t == 0) pacc0 += v;
                    else if (t == 1) pacc1 += v;
                    else pacc2 += v;
                }
            }
        }

        pacc0 += __shfl_xor(pacc0, 16); pacc0 += __shfl_xor(pacc0, 32);
        pacc1 += __shfl_xor(pacc1, 16); pacc1 += __shfl_xor(pacc1, 32);
        pacc2 += __shfl_xor(pacc2, 16); pacc2 += __shfl_xor(pacc2, 32);

        if (n < N) {
            const float inv = (dg > 0) ? 1.f / (float)dg : 0.f;
            if (lane < 16) {
                zl[wave][ni][lane]      = (_Float16)(pacc0 * inv);
                zl[wave][ni][lane + 16] = (_Float16)(pacc1 * inv);
                zl[wave][ni][lane + 32] = (_Float16)(pacc2 * inv);
            }
            if (lane < 8) {   // k=48 -> 1.0 (bias activator), k=49..63 -> 0
                const unsigned int v = (lane == 0) ? 0x00003C00u : 0u; // {1.0h, 0h}
                *reinterpret_cast<unsigned int*>(&zl[wave][ni][48 + lane * 2]) = v;
            }
        } else if (lane < 32) {   // tail: zero the row so the MFMA sees no NaNs
            *reinterpret_cast<unsigned int*>(&zl[wave][ni][lane * 2]) = 0u;
        }
    }

    // --- batched node MLP: h[16 nodes][32] = ReLU(z * W2^T + b2) ---
    __builtin_amdgcn_wave_barrier();
    const _Float16* zr = &zl[wave][col][0];
    const f16x8 A0 = *reinterpret_cast<const f16x8*>(zr + kg * 8);        // k 0..31
    const f16x8 A1 = *reinterpret_cast<const f16x8*>(zr + 32 + kg * 8);   // k 32..63

#pragma unroll
    for (int t = 0; t < 2; ++t) {
        f32x4 h = {0.f, 0.f, 0.f, 0.f};
        h = __builtin_amdgcn_mfma_f32_16x16x32_f16(A0, Wf[t][0], h, 0, 0, 0);
        h = __builtin_amdgcn_mfma_f32_16x16x32_f16(A1, Wf[t][1], h, 0, 0, 0);
#pragma unroll
        for (int r = 0; r < 4; ++r) {
            const int node = nb0 + kg * 4 + r;     // C row = node-in-batch
            if (node < N)
                out[(size_t)node * OUT_DIM + t * 16 + col] = fmaxf(h[r], 0.f);
        }
    }
}

// ---------------------------------------------------------------------------
extern "C" void kernel_launch(void* const* d_in, const int* in_sizes, int n_in,
                              void* d_out, int out_size, void* d_ws, size_t ws_size,
                              hipStream_t stream) {
    const float* y  = (const float*)d_in[0];
    const float* ex = (const float*)d_in[1];
    const float* W1 = (const float*)d_in[2];
    const float* b1 = (const float*)d_in[3];
    const float* W2 = (const float*)d_in[4];
    const float* b2 = (const float*)d_in[5];
    const int* src  = (const int*)d_in[6];
    const int* dst  = (const int*)d_in[7];

    const int N = in_sizes[0] / NODE_DIM;   // 100000
    const int E = in_sizes[6];              // 1600000
    const int NP = (N + NXCD - 1) / NXCD;   // per-XCD cursor stride
    const int NC = ((NXCD * NP + 3) / 4) * 4;

    // workspace: cursor | meta | yh | exh  (~83 MB)
    int* cursor = (int*)d_ws;                                   // NC ints
    size_t off  = ((size_t)NC * sizeof(int) + 255) & ~(size_t)255;
    int2* meta  = (int2*)((char*)d_ws + off);                   // N x MAXDEG int2
    _Float16* yh = (_Float16*)((char*)meta + (size_t)N * MAXDEG * sizeof(int2));
    _Float16* exh = (_Float16*)((char*)yh + (size_t)N * NODE_DIM * sizeof(_Float16));

    const int CBy = (N * NODE_DIM / 8 + 255) / 256;         // y cvt blocks
    const int CBe = (E * EDGE_DIM / 8 + 255) / 256;         // ex cvt blocks

    hipMemsetAsync(cursor, 0, (size_t)NC * sizeof(int), stream);

    prep_kernel<<<CBy + CBe, 256, 0, stream>>>(y, yh, CBy, ex, exh, N, E);

    const int K = (E + 2047) / 2048;        // chunks; 8 blocks per chunk
    scatter_kernel<<<K * NXCD, 256, 0, stream>>>(dst, src, cursor, meta, E, NP);

    const int NB = (N + NPW * 4 - 1) / (NPW * 4);   // 16 nodes/wave, 4 waves/block
    fused_kernel<<<NB, 256, 0, stream>>>(yh, exh, W1, b1, W2, b2,
                                         cursor, meta, (float*)d_out, N, NP);
}

// Round 21
// 197.626 us; speedup vs baseline: 1.0513x; 1.0513x over previous
//
#include <hip/hip_runtime.h>

#define NODE_DIM 32
#define EDGE_DIM 16
#define DD 48          // NODE_DIM + EDGE_DIM
#define OUT_DIM 32
#define MAXDEG 64      // bucket capacity (Poisson(16): max deg ~44)
#define STAGED 32      // bucket entries staged in LDS (P(deg>32) ~ 2e-4)
#define NXCD 8
#define NPW 16         // nodes per wave (one MFMA M-tile for the node MLP)

typedef _Float16 f16x8 __attribute__((ext_vector_type(8)));
typedef float f32x4 __attribute__((ext_vector_type(4)));

// ---------------------------------------------------------------------------
// 1) prep (pure streaming): y -> fp16; ex -> fp16
// ---------------------------------------------------------------------------
__global__ __launch_bounds__(256)
void prep_kernel(const float* __restrict__ y, _Float16* __restrict__ yh, int CBy,
                 const float* __restrict__ ex, _Float16* __restrict__ exh,
                 int N, int E) {
    int b = blockIdx.x;
    if (b < CBy) {   // y -> fp16, 8 floats/thread
        size_t i = ((size_t)b * 256 + threadIdx.x) * 8;
        if (i < (size_t)N * NODE_DIM) {
            const float4* s0 = reinterpret_cast<const float4*>(y + i);
            const float4 a = s0[0], c = s0[1];
            f16x8 h = {(_Float16)a.x, (_Float16)a.y, (_Float16)a.z, (_Float16)a.w,
                       (_Float16)c.x, (_Float16)c.y, (_Float16)c.z, (_Float16)c.w};
            *reinterpret_cast<f16x8*>(yh + i) = h;
        }
        return;
    }
    b -= CBy;        // ex -> fp16, 8 floats/thread
    size_t i = ((size_t)b * 256 + threadIdx.x) * 8;
    if (i < (size_t)E * EDGE_DIM) {
        const float4* s0 = reinterpret_cast<const float4*>(ex + i);
        const float4 a = s0[0], c = s0[1];
        f16x8 h = {(_Float16)a.x, (_Float16)a.y, (_Float16)a.z, (_Float16)a.w,
                   (_Float16)c.x, (_Float16)c.y, (_Float16)c.z, (_Float16)c.w};
        *reinterpret_cast<f16x8*>(exh + i) = h;
    }
}

// ---------------------------------------------------------------------------
// 2) scatter, XCD-partitioned (proven ~45us)
// ---------------------------------------------------------------------------
__global__ __launch_bounds__(256)
void scatter_kernel(const int* __restrict__ dst, const int* __restrict__ src,
                    int* __restrict__ cursor, int2* __restrict__ meta,
                    int E, int NP) {
    const int xcd = blockIdx.x & (NXCD - 1);
    const int c   = blockIdx.x >> 3;
    const int base = c * 2048 + threadIdx.x * 8;
    if (base >= E) return;

    int dv[8], sv[8];
    if (base + 8 <= E) {
        *reinterpret_cast<int4*>(dv)     = *reinterpret_cast<const int4*>(dst + base);
        *reinterpret_cast<int4*>(dv + 4) = *reinterpret_cast<const int4*>(dst + base + 4);
        *reinterpret_cast<int4*>(sv)     = *reinterpret_cast<const int4*>(src + base);
        *reinterpret_cast<int4*>(sv + 4) = *reinterpret_cast<const int4*>(src + base + 4);
    } else {
#pragma unroll
        for (int i = 0; i < 8; ++i) {
            dv[i] = (base + i < E) ? dst[base + i] : -1;
            sv[i] = (base + i < E) ? src[base + i] : 0;
        }
    }
#pragma unroll
    for (int i = 0; i < 8; ++i) {
        const int d = dv[i];
        if (d >= 0 && (d & (NXCD - 1)) == xcd && base + i < E) {
            int pos = atomicAdd(&cursor[xcd * NP + (d >> 3)], 1);
            if (pos < MAXDEG)
                meta[(size_t)d * MAXDEG + pos] = make_int2(base + i, sv[i]);
        }
    }
}

// ---------------------------------------------------------------------------
// 3) fused: wave owns 16 nodes. r17-style full upfront staging (low VGPR)
//    but only the first 32 bucket entries per node live in LDS (16 KB);
//    the rare deg>32 groups read meta directly from global (L2-hot).
//    Node-MLP W2/b2 fragments are built in the EPILOGUE (frees 16 VGPRs
//    across the main loop -> stay under the 64-VGPR occupancy cliff).
// ---------------------------------------------------------------------------
__global__ __launch_bounds__(256)
void fused_kernel(const _Float16* __restrict__ yh, const _Float16* __restrict__ exh,
                  const float* __restrict__ W1, const float* __restrict__ b1,
                  const float* __restrict__ W2, const float* __restrict__ b2,
                  const int* __restrict__ cursor, const int2* __restrict__ meta,
                  float* __restrict__ out, int N, int NP) {
    __shared__ int2 mlds[4][NPW][STAGED];  // 16 KB: first 32 entries per node
    __shared__ _Float16 zl[4][NPW][64];    // 8 KB: z rows (48 z | 1.0 | 0s)

    const int wave = threadIdx.x >> 6;
    const int lane = threadIdx.x & 63;
    const int col = lane & 15;            // MFMA col / A-row index
    const int kg  = lane >> 4;            // k-group 0..3

    // --- edge-MLP B fragments (W1; b1 folded at kg==3, j==7 of Bhi) ---
    f16x8 Blo[3], Bhi[3];
#pragma unroll
    for (int t = 0; t < 3; ++t) {
        const float* wr = W1 + (size_t)(t * 16 + col) * DD;
#pragma unroll
        for (int j = 0; j < 8; ++j) {
            Blo[t][j] = (_Float16)wr[kg * 8 + j];
            Bhi[t][j] = (_Float16)0.f;
        }
        if (kg < 2) {
#pragma unroll
            for (int j = 0; j < 8; ++j)
                Bhi[t][j] = (_Float16)wr[NODE_DIM + kg * 8 + j];
        }
        if (kg == 3) Bhi[t][7] = (_Float16)b1[t * 16 + col];
    }

    const int nb0 = (blockIdx.x * 4 + wave) * NPW;

    // --- one lane-parallel cursor load for all 16 nodes ---
    int dgv = 0;
    if (lane < NPW) {
        const int n = nb0 + lane;
        if (n < N) dgv = cursor[(n & (NXCD - 1)) * NP + (n >> 3)];
    }

    // --- stage first 32 bucket entries of all 16 nodes (lanes 0..31) ---
#pragma unroll
    for (int ni = 0; ni < NPW; ++ni) {
        const int cnt_i = min(__shfl(dgv, ni), STAGED);
        const int n = nb0 + ni;
        if (lane < STAGED)
            mlds[wave][ni][lane] = (lane < cnt_i && n < N)
                                       ? meta[(size_t)n * MAXDEG + lane]
                                       : make_int2(0, 0);
    }
    __builtin_amdgcn_wave_barrier();

    for (int ni = 0; ni < NPW; ++ni) {
        const int n = nb0 + ni;
        const int dg = __shfl(dgv, ni);
        const int cnt = min(dg, MAXDEG);

        float pacc0 = 0.f, pacc1 = 0.f, pacc2 = 0.f;
        const int ngroups = (cnt + 15) >> 4;

        for (int g = 0; g < ngroups; ++g) {
            const int row = g * 16 + col;
            const bool valid = row < cnt;
            // staged for row<32; rare deg>32 rows read global meta (L2-hot)
            const int2 md = (row < STAGED)
                                ? mlds[wave][ni][row]
                                : (valid ? meta[(size_t)n * MAXDEG + row]
                                         : make_int2(0, 0));
            const int eid = md.x, sv = md.y;

            f16x8 alo = *reinterpret_cast<const f16x8*>(
                yh + (size_t)sv * NODE_DIM + kg * 8);

            f16x8 ahi;
            if (kg < 2) {
                ahi = *reinterpret_cast<const f16x8*>(
                    exh + (size_t)eid * EDGE_DIM + kg * 8);
            } else {
#pragma unroll
                for (int j = 0; j < 8; ++j) ahi[j] = (_Float16)0.f;
                if (kg == 3) ahi[7] = (_Float16)1.f;   // activates b1
            }

            if (!valid) {   // pads contribute exactly 0
#pragma unroll
                for (int j = 0; j < 8; ++j) { alo[j] = (_Float16)0.f; ahi[j] = (_Float16)0.f; }
            }

#pragma unroll
            for (int t = 0; t < 3; ++t) {
                f32x4 c = {0.f, 0.f, 0.f, 0.f};
                c = __builtin_amdgcn_mfma_f32_16x16x32_f16(alo, Blo[t], c, 0, 0, 0);
                c = __builtin_amdgcn_mfma_f32_16x16x32_f16(ahi, Bhi[t], c, 0, 0, 0);
#pragma unroll
                for (int r = 0; r < 4; ++r) {
                    const float v = fmaxf(c[r], 0.f);  // b1 already inside
                    if (t == 0) pacc0 += v;
                    else if (t == 1) pacc1 += v;
                    else pacc2 += v;
                }
            }
        }

        pacc0 += __shfl_xor(pacc0, 16); pacc0 += __shfl_xor(pacc0, 32);
        pacc1 += __shfl_xor(pacc1, 16); pacc1 += __shfl_xor(pacc1, 32);
        pacc2 += __shfl_xor(pacc2, 16); pacc2 += __shfl_xor(pacc2, 32);

        if (n < N) {
            const float inv = (dg > 0) ? 1.f / (float)dg : 0.f;
            if (lane < 16) {
                zl[wave][ni][lane]      = (_Float16)(pacc0 * inv);
                zl[wave][ni][lane + 16] = (_Float16)(pacc1 * inv);
                zl[wave][ni][lane + 32] = (_Float16)(pacc2 * inv);
            }
            if (lane < 8) {   // k=48 -> 1.0 (bias activator), k=49..63 -> 0
                const unsigned int v = (lane == 0) ? 0x00003C00u : 0u; // {1.0h, 0h}
                *reinterpret_cast<unsigned int*>(&zl[wave][ni][48 + lane * 2]) = v;
            }
        } else if (lane < 32) {   // tail: zero the row so the MFMA sees no NaNs
            *reinterpret_cast<unsigned int*>(&zl[wave][ni][lane * 2]) = 0u;
        }
    }

    // --- epilogue: build node-MLP fragments HERE (not live in main loop) ---
    f16x8 Wf[2][2];
#pragma unroll
    for (int t = 0; t < 2; ++t) {
#pragma unroll
        for (int c = 0; c < 2; ++c) {
            f16x8 v;
#pragma unroll
            for (int j = 0; j < 8; ++j) {
                const int k = c * 32 + kg * 8 + j;
                float w = 0.f;
                if (k < DD)       w = W2[(size_t)(t * 16 + col) * DD + k];
                else if (k == DD) w = b2[t * 16 + col];
                v[j] = (_Float16)w;
            }
            Wf[t][c] = v;
        }
    }

    // --- batched node MLP: h[16 nodes][32] = ReLU(z * W2^T + b2) ---
    __builtin_amdgcn_wave_barrier();
    const _Float16* zr = &zl[wave][col][0];
    const f16x8 A0 = *reinterpret_cast<const f16x8*>(zr + kg * 8);        // k 0..31
    const f16x8 A1 = *reinterpret_cast<const f16x8*>(zr + 32 + kg * 8);   // k 32..63

#pragma unroll
    for (int t = 0; t < 2; ++t) {
        f32x4 h = {0.f, 0.f, 0.f, 0.f};
        h = __builtin_amdgcn_mfma_f32_16x16x32_f16(A0, Wf[t][0], h, 0, 0, 0);
        h = __builtin_amdgcn_mfma_f32_16x16x32_f16(A1, Wf[t][1], h, 0, 0, 0);
#pragma unroll
        for (int r = 0; r < 4; ++r) {
            const int node = nb0 + kg * 4 + r;     // C row = node-in-batch
            if (node < N)
                out[(size_t)node * OUT_DIM + t * 16 + col] = fmaxf(h[r], 0.f);
        }
    }
}

// ---------------------------------------------------------------------------
extern "C" void kernel_launch(void* const* d_in, const int* in_sizes, int n_in,
                              void* d_out, int out_size, void* d_ws, size_t ws_size,
                              hipStream_t stream) {
    const float* y  = (const float*)d_in[0];
    const float* ex = (const float*)d_in[1];
    const float* W1 = (const float*)d_in[2];
    const float* b1 = (const float*)d_in[3];
    const float* W2 = (const float*)d_in[4];
    const float* b2 = (const float*)d_in[5];
    const int* src  = (const int*)d_in[6];
    const int* dst  = (const int*)d_in[7];

    const int N = in_sizes[0] / NODE_DIM;   // 100000
    const int E = in_sizes[6];              // 1600000
    const int NP = (N + NXCD - 1) / NXCD;   // per-XCD cursor stride
    const int NC = ((NXCD * NP + 3) / 4) * 4;

    // workspace: cursor | meta | yh | exh  (~83 MB)
    int* cursor = (int*)d_ws;                                   // NC ints
    size_t off  = ((size_t)NC * sizeof(int) + 255) & ~(size_t)255;
    int2* meta  = (int2*)((char*)d_ws + off);                   // N x MAXDEG int2
    _Float16* yh = (_Float16*)((char*)meta + (size_t)N * MAXDEG * sizeof(int2));
    _Float16* exh = (_Float16*)((char*)yh + (size_t)N * NODE_DIM * sizeof(_Float16));

    const int CBy = (N * NODE_DIM / 8 + 255) / 256;         // y cvt blocks
    const int CBe = (E * EDGE_DIM / 8 + 255) / 256;         // ex cvt blocks

    hipMemsetAsync(cursor, 0, (size_t)NC * sizeof(int), stream);

    prep_kernel<<<CBy + CBe, 256, 0, stream>>>(y, yh, CBy, ex, exh, N, E);

    const int K = (E + 2047) / 2048;        // chunks; 8 blocks per chunk
    scatter_kernel<<<K * NXCD, 256, 0, stream>>>(dst, src, cursor, meta, E, NP);

    const int NB = (N + NPW * 4 - 1) / (NPW * 4);   // 16 nodes/wave, 4 waves/block
    fused_kernel<<<NB, 256, 0, stream>>>(yh, exh, W1, b1, W2, b2,
                                         cursor, meta, (float*)d_out, N, NP);
}

// Round 22
// 173.737 us; speedup vs baseline: 1.1959x; 1.1375x over previous
//
#include <hip/hip_runtime.h>

#define NODE_DIM 32
#define EDGE_DIM 16
#define DD 48          // NODE_DIM + EDGE_DIM
#define OUT_DIM 32
#define MAXDEG 64      // bucket capacity (Poisson(16): max deg ~44)
#define STAGED 32      // bucket entries staged in LDS (P(deg>32) ~ 2e-4)
#define NXCD 8
#define NPW 8          // nodes per wave

typedef _Float16 f16x8 __attribute__((ext_vector_type(8)));
typedef float f32x4 __attribute__((ext_vector_type(4)));

// ---------------------------------------------------------------------------
// 1) prep_scatter, GROUP-interleaved: roles assigned per 8-block group via
//    Bresenham so scatter groups (latency-bound atomics) and cvt groups
//    (BW-bound streaming) co-run on the machine. 8-block alignment keeps
//    blockIdx%8 == XCD == dst%8 for the XCD-private cursor trick.
// ---------------------------------------------------------------------------
__global__ __launch_bounds__(256)
void prep_scatter_kernel(const int* __restrict__ dst, const int* __restrict__ src,
                         int* __restrict__ cursor, int2* __restrict__ meta,
                         int E, int NP, int K, int G,
                         const float* __restrict__ y, _Float16* __restrict__ yh,
                         int CBy, const float* __restrict__ ex,
                         _Float16* __restrict__ exh, int N) {
    const int b  = blockIdx.x;
    const int g  = b >> 3;
    const int r8 = b & 7;                       // == physical XCD (round-robin)
    const long long gk = (long long)g * K;
    const int s0 = (int)(gk / G);
    const int s1 = (int)((gk + K) / G);

    if (s1 > s0) {   // ---- scatter group: chunk s0, this block does dst%8==r8
        const int base = s0 * 2048 + threadIdx.x * 8;
        if (base >= E) return;
        int dv[8], sv[8];
        if (base + 8 <= E) {
            *reinterpret_cast<int4*>(dv)     = *reinterpret_cast<const int4*>(dst + base);
            *reinterpret_cast<int4*>(dv + 4) = *reinterpret_cast<const int4*>(dst + base + 4);
            *reinterpret_cast<int4*>(sv)     = *reinterpret_cast<const int4*>(src + base);
            *reinterpret_cast<int4*>(sv + 4) = *reinterpret_cast<const int4*>(src + base + 4);
        } else {
#pragma unroll
            for (int i = 0; i < 8; ++i) {
                dv[i] = (base + i < E) ? dst[base + i] : -1;
                sv[i] = (base + i < E) ? src[base + i] : 0;
            }
        }
#pragma unroll
        for (int i = 0; i < 8; ++i) {
            const int d = dv[i];
            if (d >= 0 && (d & (NXCD - 1)) == r8 && base + i < E) {
                int pos = atomicAdd(&cursor[r8 * NP + (d >> 3)], 1);
                if (pos < MAXDEG)
                    meta[(size_t)d * MAXDEG + pos] = make_int2(base + i, sv[i]);
            }
        }
        return;
    }

    // ---- cvt group ----
    int cb = (g - s0) * 8 + r8;
    if (cb < CBy) {   // y -> fp16, 8 floats/thread
        size_t i = ((size_t)cb * 256 + threadIdx.x) * 8;
        if (i < (size_t)N * NODE_DIM) {
            const float4* p = reinterpret_cast<const float4*>(y + i);
            const float4 a = p[0], c = p[1];
            f16x8 h = {(_Float16)a.x, (_Float16)a.y, (_Float16)a.z, (_Float16)a.w,
                       (_Float16)c.x, (_Float16)c.y, (_Float16)c.z, (_Float16)c.w};
            *reinterpret_cast<f16x8*>(yh + i) = h;
        }
        return;
    }
    cb -= CBy;        // ex -> fp16, 8 floats/thread
    size_t i = ((size_t)cb * 256 + threadIdx.x) * 8;
    if (i < (size_t)E * EDGE_DIM) {
        const float4* p = reinterpret_cast<const float4*>(ex + i);
        const float4 a = p[0], c = p[1];
        f16x8 h = {(_Float16)a.x, (_Float16)a.y, (_Float16)a.z, (_Float16)a.w,
                   (_Float16)c.x, (_Float16)c.y, (_Float16)c.z, (_Float16)c.w};
        *reinterpret_cast<f16x8*>(exh + i) = h;
    }
}

// ---------------------------------------------------------------------------
// 2) fused: wave owns 8 nodes (NPW=8). 12 KB LDS + ~40 VGPR -> 8 blocks/CU
//    = 32 waves/CU (HW cap); grid 3125 blocks = 12/CU for load balance.
//    Structure otherwise r21: upfront 32-entry staging, rare deg>32 rows
//    read global meta; b1/b2 folded into MFMA K; epilogue node-MLP MFMA.
// ---------------------------------------------------------------------------
__global__ __launch_bounds__(256)
void fused_kernel(const _Float16* __restrict__ yh, const _Float16* __restrict__ exh,
                  const float* __restrict__ W1, const float* __restrict__ b1,
                  const float* __restrict__ W2, const float* __restrict__ b2,
                  const int* __restrict__ cursor, const int2* __restrict__ meta,
                  float* __restrict__ out, int N, int NP) {
    __shared__ int2 mlds[4][NPW][STAGED];  // 8 KB
    __shared__ _Float16 zl[4][NPW][64];    // 4 KB: z rows (48 z | 1.0 | 0s)

    const int wave = threadIdx.x >> 6;
    const int lane = threadIdx.x & 63;
    const int col = lane & 15;            // MFMA col / A-row index
    const int kg  = lane >> 4;            // k-group 0..3

    // --- edge-MLP B fragments (W1; b1 folded at kg==3, j==7 of Bhi) ---
    f16x8 Blo[3], Bhi[3];
#pragma unroll
    for (int t = 0; t < 3; ++t) {
        const float* wr = W1 + (size_t)(t * 16 + col) * DD;
#pragma unroll
        for (int j = 0; j < 8; ++j) {
            Blo[t][j] = (_Float16)wr[kg * 8 + j];
            Bhi[t][j] = (_Float16)0.f;
        }
        if (kg < 2) {
#pragma unroll
            for (int j = 0; j < 8; ++j)
                Bhi[t][j] = (_Float16)wr[NODE_DIM + kg * 8 + j];
        }
        if (kg == 3) Bhi[t][7] = (_Float16)b1[t * 16 + col];
    }

    const int nb0 = (blockIdx.x * 4 + wave) * NPW;

    // --- one lane-parallel cursor load for all 8 nodes ---
    int dgv = 0;
    if (lane < NPW) {
        const int n = nb0 + lane;
        if (n < N) dgv = cursor[(n & (NXCD - 1)) * NP + (n >> 3)];
    }

    // --- stage first 32 bucket entries of all 8 nodes (lanes 0..31) ---
#pragma unroll
    for (int ni = 0; ni < NPW; ++ni) {
        const int cnt_i = min(__shfl(dgv, ni), STAGED);
        const int n = nb0 + ni;
        if (lane < STAGED)
            mlds[wave][ni][lane] = (lane < cnt_i && n < N)
                                       ? meta[(size_t)n * MAXDEG + lane]
                                       : make_int2(0, 0);
    }
    __builtin_amdgcn_wave_barrier();

    for (int ni = 0; ni < NPW; ++ni) {
        const int n = nb0 + ni;
        const int dg = __shfl(dgv, ni);
        const int cnt = min(dg, MAXDEG);

        float pacc0 = 0.f, pacc1 = 0.f, pacc2 = 0.f;
        const int ngroups = (cnt + 15) >> 4;

        for (int g = 0; g < ngroups; ++g) {
            const int row = g * 16 + col;
            const bool valid = row < cnt;
            const int2 md = (row < STAGED)
                                ? mlds[wave][ni][row]
                                : (valid ? meta[(size_t)n * MAXDEG + row]
                                         : make_int2(0, 0));
            const int eid = md.x, sv = md.y;

            f16x8 alo = *reinterpret_cast<const f16x8*>(
                yh + (size_t)sv * NODE_DIM + kg * 8);

            f16x8 ahi;
            if (kg < 2) {
                ahi = *reinterpret_cast<const f16x8*>(
                    exh + (size_t)eid * EDGE_DIM + kg * 8);
            } else {
#pragma unroll
                for (int j = 0; j < 8; ++j) ahi[j] = (_Float16)0.f;
                if (kg == 3) ahi[7] = (_Float16)1.f;   // activates b1
            }

            if (!valid) {   // pads contribute exactly 0
#pragma unroll
                for (int j = 0; j < 8; ++j) { alo[j] = (_Float16)0.f; ahi[j] = (_Float16)0.f; }
            }

#pragma unroll
            for (int t = 0; t < 3; ++t) {
                f32x4 c = {0.f, 0.f, 0.f, 0.f};
                c = __builtin_amdgcn_mfma_f32_16x16x32_f16(alo, Blo[t], c, 0, 0, 0);
                c = __builtin_amdgcn_mfma_f32_16x16x32_f16(ahi, Bhi[t], c, 0, 0, 0);
#pragma unroll
                for (int r = 0; r < 4; ++r) {
                    const float v = fmaxf(c[r], 0.f);  // b1 already inside
                    if (t == 0) pacc0 += v;
                    else if (t == 1) pacc1 += v;
                    else pacc2 += v;
                }
            }
        }

        pacc0 += __shfl_xor(pacc0, 16); pacc0 += __shfl_xor(pacc0, 32);
        pacc1 += __shfl_xor(pacc1, 16); pacc1 += __shfl_xor(pacc1, 32);
        pacc2 += __shfl_xor(pacc2, 16); pacc2 += __shfl_xor(pacc2, 32);

        if (n < N) {
            const float inv = (dg > 0) ? 1.f / (float)dg : 0.f;
            if (lane < 16) {
                zl[wave][ni][lane]      = (_Float16)(pacc0 * inv);
                zl[wave][ni][lane + 16] = (_Float16)(pacc1 * inv);
                zl[wave][ni][lane + 32] = (_Float16)(pacc2 * inv);
            }
            if (lane < 8) {   // k=48 -> 1.0 (bias activator), k=49..63 -> 0
                const unsigned int v = (lane == 0) ? 0x00003C00u : 0u; // {1.0h, 0h}
                *reinterpret_cast<unsigned int*>(&zl[wave][ni][48 + lane * 2]) = v;
            }
        } else if (lane < 32) {   // tail: zero the row so the MFMA sees no NaNs
            *reinterpret_cast<unsigned int*>(&zl[wave][ni][lane * 2]) = 0u;
        }
    }

    // --- epilogue: node-MLP fragments built here (not live in main loop) ---
    f16x8 Wf[2][2];
#pragma unroll
    for (int t = 0; t < 2; ++t) {
#pragma unroll
        for (int c = 0; c < 2; ++c) {
            f16x8 v;
#pragma unroll
            for (int j = 0; j < 8; ++j) {
                const int k = c * 32 + kg * 8 + j;
                float w = 0.f;
                if (k < DD)       w = W2[(size_t)(t * 16 + col) * DD + k];
                else if (k == DD) w = b2[t * 16 + col];
                v[j] = (_Float16)w;
            }
            Wf[t][c] = v;
        }
    }

    // --- batched node MLP: rows 0..7 are real nodes (A rows 8..15 clamp to
    //     rows 0..7; their C rows are store-masked) ---
    __builtin_amdgcn_wave_barrier();
    const _Float16* zr = &zl[wave][col & (NPW - 1)][0];
    const f16x8 A0 = *reinterpret_cast<const f16x8*>(zr + kg * 8);        // k 0..31
    const f16x8 A1 = *reinterpret_cast<const f16x8*>(zr + 32 + kg * 8);   // k 32..63

#pragma unroll
    for (int t = 0; t < 2; ++t) {
        f32x4 h = {0.f, 0.f, 0.f, 0.f};
        h = __builtin_amdgcn_mfma_f32_16x16x32_f16(A0, Wf[t][0], h, 0, 0, 0);
        h = __builtin_amdgcn_mfma_f32_16x16x32_f16(A1, Wf[t][1], h, 0, 0, 0);
#pragma unroll
        for (int r = 0; r < 4; ++r) {
            const int mrow = kg * 4 + r;           // C row = node-in-batch
            const int node = nb0 + mrow;
            if (mrow < NPW && node < N)
                out[(size_t)node * OUT_DIM + t * 16 + col] = fmaxf(h[r], 0.f);
        }
    }
}

// ---------------------------------------------------------------------------
extern "C" void kernel_launch(void* const* d_in, const int* in_sizes, int n_in,
                              void* d_out, int out_size, void* d_ws, size_t ws_size,
                              hipStream_t stream) {
    const float* y  = (const float*)d_in[0];
    const float* ex = (const float*)d_in[1];
    const float* W1 = (const float*)d_in[2];
    const float* b1 = (const float*)d_in[3];
    const float* W2 = (const float*)d_in[4];
    const float* b2 = (const float*)d_in[5];
    const int* src  = (const int*)d_in[6];
    const int* dst  = (const int*)d_in[7];

    const int N = in_sizes[0] / NODE_DIM;   // 100000
    const int E = in_sizes[6];              // 1600000
    const int NP = (N + NXCD - 1) / NXCD;   // per-XCD cursor stride
    const int NC = ((NXCD * NP + 3) / 4) * 4;

    // workspace: cursor | meta | yh | exh  (~83 MB)
    int* cursor = (int*)d_ws;                                   // NC ints
    size_t off  = ((size_t)NC * sizeof(int) + 255) & ~(size_t)255;
    int2* meta  = (int2*)((char*)d_ws + off);                   // N x MAXDEG int2
    _Float16* yh = (_Float16*)((char*)meta + (size_t)N * MAXDEG * sizeof(int2));
    _Float16* exh = (_Float16*)((char*)yh + (size_t)N * NODE_DIM * sizeof(_Float16));

    const int CBy = (N * NODE_DIM / 8 + 255) / 256;         // y cvt blocks
    const int CBe = (E * EDGE_DIM / 8 + 255) / 256;         // ex cvt blocks
    const int K   = (E + 2047) / 2048;                      // scatter chunks
    const int CG  = (CBy + CBe + 7) / 8;                    // cvt groups
    const int G   = K + CG;                                 // total groups

    hipMemsetAsync(cursor, 0, (size_t)NC * sizeof(int), stream);

    prep_scatter_kernel<<<G * 8, 256, 0, stream>>>(dst, src, cursor, meta,
                                                   E, NP, K, G,
                                                   y, yh, CBy, ex, exh, N);

    const int NB = (N + NPW * 4 - 1) / (NPW * 4);   // 8 nodes/wave, 4 waves/block
    fused_kernel<<<NB, 256, 0, stream>>>(yh, exh, W1, b1, W2, b2,
                                         cursor, meta, (float*)d_out, N, NP);
}

// Round 23
// 168.111 us; speedup vs baseline: 1.2359x; 1.0335x over previous
//
#include <hip/hip_runtime.h>

#define NODE_DIM 32
#define EDGE_DIM 16
#define DD 48          // NODE_DIM + EDGE_DIM
#define OUT_DIM 32
#define MAXDEG 64      // bucket capacity (Poisson(16): max deg ~44)
#define STAGED 32      // bucket entries staged in LDS (P(deg>32) ~ 2e-4)
#define NXCD 8
#define NPW 8          // nodes per wave

typedef _Float16 f16x8 __attribute__((ext_vector_type(8)));
typedef float f32x4 __attribute__((ext_vector_type(4)));

// ---------------------------------------------------------------------------
// 1) prep_scatter, GROUP-interleaved (r22-proven): scatter groups (atomics)
//    co-run with cvt groups (streaming); 8-block alignment keeps
//    blockIdx%8 == XCD == dst%8 for the XCD-private cursor trick.
// ---------------------------------------------------------------------------
__global__ __launch_bounds__(256)
void prep_scatter_kernel(const int* __restrict__ dst, const int* __restrict__ src,
                         int* __restrict__ cursor, int2* __restrict__ meta,
                         int E, int NP, int K, int G,
                         const float* __restrict__ y, _Float16* __restrict__ yh,
                         int CBy, const float* __restrict__ ex,
                         _Float16* __restrict__ exh, int N) {
    const int b  = blockIdx.x;
    const int g  = b >> 3;
    const int r8 = b & 7;                       // == physical XCD (round-robin)
    const long long gk = (long long)g * K;
    const int s0 = (int)(gk / G);
    const int s1 = (int)((gk + K) / G);

    if (s1 > s0) {   // ---- scatter group: chunk s0, this block does dst%8==r8
        const int base = s0 * 2048 + threadIdx.x * 8;
        if (base >= E) return;
        int dv[8], sv[8];
        if (base + 8 <= E) {
            *reinterpret_cast<int4*>(dv)     = *reinterpret_cast<const int4*>(dst + base);
            *reinterpret_cast<int4*>(dv + 4) = *reinterpret_cast<const int4*>(dst + base + 4);
            *reinterpret_cast<int4*>(sv)     = *reinterpret_cast<const int4*>(src + base);
            *reinterpret_cast<int4*>(sv + 4) = *reinterpret_cast<const int4*>(src + base + 4);
        } else {
#pragma unroll
            for (int i = 0; i < 8; ++i) {
                dv[i] = (base + i < E) ? dst[base + i] : -1;
                sv[i] = (base + i < E) ? src[base + i] : 0;
            }
        }
#pragma unroll
        for (int i = 0; i < 8; ++i) {
            const int d = dv[i];
            if (d >= 0 && (d & (NXCD - 1)) == r8 && base + i < E) {
                int pos = atomicAdd(&cursor[r8 * NP + (d >> 3)], 1);
                if (pos < MAXDEG)
                    meta[(size_t)d * MAXDEG + pos] = make_int2(base + i, sv[i]);
            }
        }
        return;
    }

    // ---- cvt group ----
    int cb = (g - s0) * 8 + r8;
    if (cb < CBy) {   // y -> fp16, 8 floats/thread
        size_t i = ((size_t)cb * 256 + threadIdx.x) * 8;
        if (i < (size_t)N * NODE_DIM) {
            const float4* p = reinterpret_cast<const float4*>(y + i);
            const float4 a = p[0], c = p[1];
            f16x8 h = {(_Float16)a.x, (_Float16)a.y, (_Float16)a.z, (_Float16)a.w,
                       (_Float16)c.x, (_Float16)c.y, (_Float16)c.z, (_Float16)c.w};
            *reinterpret_cast<f16x8*>(yh + i) = h;
        }
        return;
    }
    cb -= CBy;        // ex -> fp16, 8 floats/thread
    size_t i = ((size_t)cb * 256 + threadIdx.x) * 8;
    if (i < (size_t)E * EDGE_DIM) {
        const float4* p = reinterpret_cast<const float4*>(ex + i);
        const float4 a = p[0], c = p[1];
        f16x8 h = {(_Float16)a.x, (_Float16)a.y, (_Float16)a.z, (_Float16)a.w,
                   (_Float16)c.x, (_Float16)c.y, (_Float16)c.z, (_Float16)c.w};
        *reinterpret_cast<f16x8*>(exh + i) = h;
    }
}

// ---------------------------------------------------------------------------
// 2) fused: wave owns 8 nodes. Per node BOTH groups' gathers issue together
//    (4 VMEM in flight; cnt is wave-uniform so the g1 branch doesn't
//    diverge), then all 12 MFMAs. #pragma unroll 2 on the node loop lets
//    the scheduler overlap node ni+1's loads with node ni's MFMAs.
//    12 KB LDS, ~50 VGPR -> 32 waves/CU cap, grid 12/CU for balance.
// ---------------------------------------------------------------------------
__global__ __launch_bounds__(256)
void fused_kernel(const _Float16* __restrict__ yh, const _Float16* __restrict__ exh,
                  const float* __restrict__ W1, const float* __restrict__ b1,
                  const float* __restrict__ W2, const float* __restrict__ b2,
                  const int* __restrict__ cursor, const int2* __restrict__ meta,
                  float* __restrict__ out, int N, int NP) {
    __shared__ int2 mlds[4][NPW][STAGED];  // 8 KB
    __shared__ _Float16 zl[4][NPW][64];    // 4 KB: z rows (48 z | 1.0 | 0s)

    const int wave = threadIdx.x >> 6;
    const int lane = threadIdx.x & 63;
    const int col = lane & 15;            // MFMA col / A-row index
    const int kg  = lane >> 4;            // k-group 0..3

    // --- edge-MLP B fragments (W1; b1 folded at kg==3, j==7 of Bhi) ---
    f16x8 Blo[3], Bhi[3];
#pragma unroll
    for (int t = 0; t < 3; ++t) {
        const float* wr = W1 + (size_t)(t * 16 + col) * DD;
#pragma unroll
        for (int j = 0; j < 8; ++j) {
            Blo[t][j] = (_Float16)wr[kg * 8 + j];
            Bhi[t][j] = (_Float16)0.f;
        }
        if (kg < 2) {
#pragma unroll
            for (int j = 0; j < 8; ++j)
                Bhi[t][j] = (_Float16)wr[NODE_DIM + kg * 8 + j];
        }
        if (kg == 3) Bhi[t][7] = (_Float16)b1[t * 16 + col];
    }

    const int nb0 = (blockIdx.x * 4 + wave) * NPW;

    // --- one lane-parallel cursor load for all 8 nodes ---
    int dgv = 0;
    if (lane < NPW) {
        const int n = nb0 + lane;
        if (n < N) dgv = cursor[(n & (NXCD - 1)) * NP + (n >> 3)];
    }

    // --- stage first 32 bucket entries of all 8 nodes (lanes 0..31) ---
#pragma unroll
    for (int ni = 0; ni < NPW; ++ni) {
        const int cnt_i = min(__shfl(dgv, ni), STAGED);
        const int n = nb0 + ni;
        if (lane < STAGED)
            mlds[wave][ni][lane] = (lane < cnt_i && n < N)
                                       ? meta[(size_t)n * MAXDEG + lane]
                                       : make_int2(0, 0);
    }
    __builtin_amdgcn_wave_barrier();

    // constant part of the A-high fragment (kg>=2): 1.0 activator at kg3/j7
    f16x8 ahiC;
#pragma unroll
    for (int j = 0; j < 8; ++j) ahiC[j] = (_Float16)0.f;
    if (kg == 3) ahiC[7] = (_Float16)1.f;

#pragma unroll 2
    for (int ni = 0; ni < NPW; ++ni) {
        const int n = nb0 + ni;
        const int dg = __shfl(dgv, ni);
        const int cnt = min(dg, MAXDEG);

        float pacc0 = 0.f, pacc1 = 0.f, pacc2 = 0.f;

        // ---- groups 0 and 1: gathers issued together (4 VMEM in flight) ----
        {
            const bool v0 = col < cnt;
            const int2 md0 = mlds[wave][ni][col];
            f16x8 alo0 = *reinterpret_cast<const f16x8*>(
                yh + (size_t)md0.y * NODE_DIM + kg * 8);
            f16x8 ahi0 = ahiC;
            if (kg < 2)
                ahi0 = *reinterpret_cast<const f16x8*>(
                    exh + (size_t)md0.x * EDGE_DIM + kg * 8);

            f16x8 alo1, ahi1;
            const bool haveG1 = cnt > 16;      // wave-uniform branch
            if (haveG1) {
                const int2 md1 = mlds[wave][ni][16 + col];
                alo1 = *reinterpret_cast<const f16x8*>(
                    yh + (size_t)md1.y * NODE_DIM + kg * 8);
                ahi1 = ahiC;
                if (kg < 2)
                    ahi1 = *reinterpret_cast<const f16x8*>(
                        exh + (size_t)md1.x * EDGE_DIM + kg * 8);
            }

            if (!v0) {
#pragma unroll
                for (int j = 0; j < 8; ++j) { alo0[j] = (_Float16)0.f; ahi0[j] = (_Float16)0.f; }
            }
#pragma unroll
            for (int t = 0; t < 3; ++t) {
                f32x4 c = {0.f, 0.f, 0.f, 0.f};
                c = __builtin_amdgcn_mfma_f32_16x16x32_f16(alo0, Blo[t], c, 0, 0, 0);
                c = __builtin_amdgcn_mfma_f32_16x16x32_f16(ahi0, Bhi[t], c, 0, 0, 0);
#pragma unroll
                for (int r = 0; r < 4; ++r) {
                    const float v = fmaxf(c[r], 0.f);
                    if (t == 0) pacc0 += v;
                    else if (t == 1) pacc1 += v;
                    else pacc2 += v;
                }
            }

            if (haveG1) {
                const bool v1 = (16 + col) < cnt;
                if (!v1) {
#pragma unroll
                    for (int j = 0; j < 8; ++j) { alo1[j] = (_Float16)0.f; ahi1[j] = (_Float16)0.f; }
                }
#pragma unroll
                for (int t = 0; t < 3; ++t) {
                    f32x4 c = {0.f, 0.f, 0.f, 0.f};
                    c = __builtin_amdgcn_mfma_f32_16x16x32_f16(alo1, Blo[t], c, 0, 0, 0);
                    c = __builtin_amdgcn_mfma_f32_16x16x32_f16(ahi1, Bhi[t], c, 0, 0, 0);
#pragma unroll
                    for (int r = 0; r < 4; ++r) {
                        const float v = fmaxf(c[r], 0.f);
                        if (t == 0) pacc0 += v;
                        else if (t == 1) pacc1 += v;
                        else pacc2 += v;
                    }
                }
            }
        }

        // ---- rare deg>32 tail: global meta reads (L2-hot) ----
        if (cnt > STAGED) {
            const int ngroups = (cnt + 15) >> 4;
            for (int g = 2; g < ngroups; ++g) {
                const int row = g * 16 + col;
                const bool valid = row < cnt;
                const int2 md = valid ? meta[(size_t)n * MAXDEG + row]
                                      : make_int2(0, 0);
                f16x8 alo = *reinterpret_cast<const f16x8*>(
                    yh + (size_t)md.y * NODE_DIM + kg * 8);
                f16x8 ahi = ahiC;
                if (kg < 2)
                    ahi = *reinterpret_cast<const f16x8*>(
                        exh + (size_t)md.x * EDGE_DIM + kg * 8);
                if (!valid) {
#pragma unroll
                    for (int j = 0; j < 8; ++j) { alo[j] = (_Float16)0.f; ahi[j] = (_Float16)0.f; }
                }
#pragma unroll
                for (int t = 0; t < 3; ++t) {
                    f32x4 c = {0.f, 0.f, 0.f, 0.f};
                    c = __builtin_amdgcn_mfma_f32_16x16x32_f16(alo, Blo[t], c, 0, 0, 0);
                    c = __builtin_amdgcn_mfma_f32_16x16x32_f16(ahi, Bhi[t], c, 0, 0, 0);
#pragma unroll
                    for (int r = 0; r < 4; ++r) {
                        const float v = fmaxf(c[r], 0.f);
                        if (t == 0) pacc0 += v;
                        else if (t == 1) pacc1 += v;
                        else pacc2 += v;
                    }
                }
            }
        }

        pacc0 += __shfl_xor(pacc0, 16); pacc0 += __shfl_xor(pacc0, 32);
        pacc1 += __shfl_xor(pacc1, 16); pacc1 += __shfl_xor(pacc1, 32);
        pacc2 += __shfl_xor(pacc2, 16); pacc2 += __shfl_xor(pacc2, 32);

        if (n < N) {
            const float inv = (dg > 0) ? 1.f / (float)dg : 0.f;
            if (lane < 16) {
                zl[wave][ni][lane]      = (_Float16)(pacc0 * inv);
                zl[wave][ni][lane + 16] = (_Float16)(pacc1 * inv);
                zl[wave][ni][lane + 32] = (_Float16)(pacc2 * inv);
            }
            if (lane < 8) {   // k=48 -> 1.0 (bias activator), k=49..63 -> 0
                const unsigned int v = (lane == 0) ? 0x00003C00u : 0u; // {1.0h, 0h}
                *reinterpret_cast<unsigned int*>(&zl[wave][ni][48 + lane * 2]) = v;
            }
        } else if (lane < 32) {   // tail: zero the row so the MFMA sees no NaNs
            *reinterpret_cast<unsigned int*>(&zl[wave][ni][lane * 2]) = 0u;
        }
    }

    // --- epilogue: node-MLP fragments built here (not live in main loop) ---
    f16x8 Wf[2][2];
#pragma unroll
    for (int t = 0; t < 2; ++t) {
#pragma unroll
        for (int c = 0; c < 2; ++c) {
            f16x8 v;
#pragma unroll
            for (int j = 0; j < 8; ++j) {
                const int k = c * 32 + kg * 8 + j;
                float w = 0.f;
                if (k < DD)       w = W2[(size_t)(t * 16 + col) * DD + k];
                else if (k == DD) w = b2[t * 16 + col];
                v[j] = (_Float16)w;
            }
            Wf[t][c] = v;
        }
    }

    // --- batched node MLP: rows 0..7 real (A rows 8..15 clamp; C store-masked)
    __builtin_amdgcn_wave_barrier();
    const _Float16* zr = &zl[wave][col & (NPW - 1)][0];
    const f16x8 A0 = *reinterpret_cast<const f16x8*>(zr + kg * 8);        // k 0..31
    const f16x8 A1 = *reinterpret_cast<const f16x8*>(zr + 32 + kg * 8);   // k 32..63

#pragma unroll
    for (int t = 0; t < 2; ++t) {
        f32x4 h = {0.f, 0.f, 0.f, 0.f};
        h = __builtin_amdgcn_mfma_f32_16x16x32_f16(A0, Wf[t][0], h, 0, 0, 0);
        h = __builtin_amdgcn_mfma_f32_16x16x32_f16(A1, Wf[t][1], h, 0, 0, 0);
#pragma unroll
        for (int r = 0; r < 4; ++r) {
            const int mrow = kg * 4 + r;           // C row = node-in-batch
            const int node = nb0 + mrow;
            if (mrow < NPW && node < N)
                out[(size_t)node * OUT_DIM + t * 16 + col] = fmaxf(h[r], 0.f);
        }
    }
}

// ---------------------------------------------------------------------------
extern "C" void kernel_launch(void* const* d_in, const int* in_sizes, int n_in,
                              void* d_out, int out_size, void* d_ws, size_t ws_size,
                              hipStream_t stream) {
    const float* y  = (const float*)d_in[0];
    const float* ex = (const float*)d_in[1];
    const float* W1 = (const float*)d_in[2];
    const float* b1 = (const float*)d_in[3];
    const float* W2 = (const float*)d_in[4];
    const float* b2 = (const float*)d_in[5];
    const int* src  = (const int*)d_in[6];
    const int* dst  = (const int*)d_in[7];

    const int N = in_sizes[0] / NODE_DIM;   // 100000
    const int E = in_sizes[6];              // 1600000
    const int NP = (N + NXCD - 1) / NXCD;   // per-XCD cursor stride
    const int NC = ((NXCD * NP + 3) / 4) * 4;

    // workspace: cursor | meta | yh | exh  (~83 MB)
    int* cursor = (int*)d_ws;                                   // NC ints
    size_t off  = ((size_t)NC * sizeof(int) + 255) & ~(size_t)255;
    int2* meta  = (int2*)((char*)d_ws + off);                   // N x MAXDEG int2
    _Float16* yh = (_Float16*)((char*)meta + (size_t)N * MAXDEG * sizeof(int2));
    _Float16* exh = (_Float16*)((char*)yh + (size_t)N * NODE_DIM * sizeof(_Float16));

    const int CBy = (N * NODE_DIM / 8 + 255) / 256;         // y cvt blocks
    const int CBe = (E * EDGE_DIM / 8 + 255) / 256;         // ex cvt blocks
    const int K   = (E + 2047) / 2048;                      // scatter chunks
    const int CG  = (CBy + CBe + 7) / 8;                    // cvt groups
    const int G   = K + CG;                                 // total groups

    hipMemsetAsync(cursor, 0, (size_t)NC * sizeof(int), stream);

    prep_scatter_kernel<<<G * 8, 256, 0, stream>>>(dst, src, cursor, meta,
                                                   E, NP, K, G,
                                                   y, yh, CBy, ex, exh, N);

    const int NB = (N + NPW * 4 - 1) / (NPW * 4);   // 8 nodes/wave, 4 waves/block
    fused_kernel<<<NB, 256, 0, stream>>>(yh, exh, W1, b1, W2, b2,
                                         cursor, meta, (float*)d_out, N, NP);
}